// Round 5
// baseline (737.552 us; speedup 1.0000x reference)
//
#include <hip/hip_runtime.h>
#include <hip/hip_bf16.h>

#define B_ 8
#define N_ 4096
#define C_ 512
#define H_ 4
#define EPS_ 1e-4f
#define E60P 1.14200739e26f   // expf(60)
#define E60M 8.7565108e-27f   // expf(-60)
#define SENT 0x13579BDFu      // != 0xAAAAAAAA poison

typedef __attribute__((ext_vector_type(8))) short short8;
typedef __attribute__((ext_vector_type(4))) float floatx4;
typedef unsigned short ushort_t;

__device__ __forceinline__ float sigmoidf_(float v) {
    return 1.0f / (1.0f + expf(-v));
}

// Fragment-packed layout for GEMM operands (Z and W):
//   chunk(tile t, half w, k0, ks, f) = 512 bf16 (1 KiB) in exact MFMA lane
//   order: element lane*8+kb holds Op[t*128+w*64+f*16+(lane&15)]
//                                   [k0*64+ks*32+(lane>>4)*8+kb]
__device__ __forceinline__ int pk_off(int t, int w, int k0, int ks, int f,
                                      int lane8, int kb) {
    return ((((t * 2 + w) * 16 + k0) * 2 + ks) * 4 + f) * 512 + lane8 * 8 + kb;
}

// ---------------------------------------------------------------------------
// K_EMA: single-pass fused EMA (fwd+bwd) with decoupled-lookback scan.
// grid 1024 = chain(6b: b*8+ct) * 16 chunks (chain blocks CONTIGUOUS in bid).
// Each block: stage x-slice in LDS once -> subchunk partials -> publish
// aggregates (agent-scope) -> aggregate-only lookback over 15 siblings ->
// compute z, store fragment-packed bf16.  x read from HBM exactly once.
// ---------------------------------------------------------------------------
__global__ __launch_bounds__(256) void k_ema(
    const float* __restrict__ x, const float* __restrict__ al,
    const float* __restrict__ dl, const float* __restrict__ bl,
    const float* __restrict__ eta,
    float* __restrict__ Agg, unsigned int* __restrict__ Flag,
    ushort_t* __restrict__ Zp)
{
    __shared__ float sx[4][4096];      // 64 KiB: per-wave 64 rows x 64 chans
    __shared__ float sT[2][4][4][64];  // dir, wave, h, chan
    __shared__ float sC[2][4][64];     // dir, h, chan (block carry)

    int tid   = threadIdx.x;
    int bid   = blockIdx.x;
    int chunk = bid & 15;
    int chain = bid >> 4;              // b*8 + ct
    int ct    = chain & 7;
    int b     = chain >> 3;
    int lane  = tid & 63;
    int wave  = tid >> 6;
    int c     = ct * 64 + lane;
    int sub   = chunk * 4 + wave;      // fwd subchunk 0..63
    int t0f   = sub * 64;
    int t0b   = (63 - sub) * 64;       // bwd subchunk start (reversed time)

    // ---- stage this wave's x slice (only read of x from global)
    const float* xp = x + ((size_t)b * N_ + t0f) * C_ + c;
    float* sxe = sx[wave];
    #pragma unroll 8
    for (int i = 0; i < 64; ++i)
        sxe[i * 64 + lane] = xp[(size_t)i * C_];

    // ---- per-channel params
    float aa[4], dd[4], bb[4], ee[4];
    { float4 v = ((const float4*)al )[c]; aa[0]=v.x; aa[1]=v.y; aa[2]=v.z; aa[3]=v.w; }
    { float4 v = ((const float4*)dl )[c]; dd[0]=v.x; dd[1]=v.y; dd[2]=v.z; dd[3]=v.w; }
    { float4 v = ((const float4*)bl )[c]; bb[0]=v.x; bb[1]=v.y; bb[2]=v.z; bb[3]=v.w; }
    { float4 v = ((const float4*)eta)[c]; ee[0]=v.x; ee[1]=v.y; ee[2]=v.z; ee[3]=v.w; }

    float A[H_], rr[H_], ri[H_], Lh[H_];
    #pragma unroll
    for (int h = 0; h < H_; ++h) {
        float alpha = sigmoidf_(aa[h]);
        float delta = sigmoidf_(dd[h]);
        float beta  = sigmoidf_(bb[h]);
        A[h] = alpha * beta;
        float r = fminf(fmaxf(1.0f - alpha * delta, EPS_), 1.0f - EPS_);
        Lh[h] = logf(r);
        rr[h] = r;
        ri[h] = 1.0f / r;
    }

    // ---- subchunk partials (fwd and bwd), from LDS stash
    float ep[H_], T[H_];
    #pragma unroll
    for (int h = 0; h < H_; ++h) {
        ep[h] = expf(fminf(-Lh[h] * (float)t0f, 60.0f));
        T[h]  = 0.0f;
    }
    #pragma unroll 8
    for (int i = 0; i < 64; ++i) {
        float xv = sxe[i * 64 + lane];
        #pragma unroll
        for (int h = 0; h < H_; ++h) {
            T[h]  = fmaf(A[h] * xv, ep[h], T[h]);
            ep[h] = fminf(ep[h] * ri[h], E60P);
        }
    }
    #pragma unroll
    for (int h = 0; h < H_; ++h) sT[0][wave][h][lane] = T[h];

    #pragma unroll
    for (int h = 0; h < H_; ++h) {
        ep[h] = expf(fminf(-Lh[h] * (float)t0b, 60.0f));
        T[h]  = 0.0f;
    }
    #pragma unroll 8
    for (int j = 0; j < 64; ++j) {
        float xv = sxe[(63 - j) * 64 + lane];
        #pragma unroll
        for (int h = 0; h < H_; ++h) {
            T[h]  = fmaf(A[h] * xv, ep[h], T[h]);
            ep[h] = fminf(ep[h] * ri[h], E60P);
        }
    }
    #pragma unroll
    for (int h = 0; h < H_; ++h) sT[1][wave][h][lane] = T[h];

    __syncthreads();

    // ---- publish block aggregates (PUBLISH BEFORE ANY WAIT -> no deadlock)
    int hh = tid >> 6, cn = tid & 63;
    {
        float aF = sT[0][0][hh][cn] + sT[0][1][hh][cn]
                 + sT[0][2][hh][cn] + sT[0][3][hh][cn];
        float aB = sT[1][0][hh][cn] + sT[1][1][hh][cn]
                 + sT[1][2][hh][cn] + sT[1][3][hh][cn];
        float* ag = Agg + (size_t)bid * 512;
        __hip_atomic_store(&ag[hh * 64 + cn], aF,
                           __ATOMIC_RELAXED, __HIP_MEMORY_SCOPE_AGENT);
        __hip_atomic_store(&ag[256 + hh * 64 + cn], aB,
                           __ATOMIC_RELAXED, __HIP_MEMORY_SCOPE_AGENT);
    }
    __threadfence();
    __syncthreads();
    if (tid == 0)
        __hip_atomic_store(&Flag[bid], SENT,
                           __ATOMIC_RELEASE, __HIP_MEMORY_SCOPE_AGENT);

    // ---- aggregate-only lookback over the 15 sibling blocks of this chain
    float carF = 0.0f, carB = 0.0f;
    int base = chain << 4;
    for (int p = 0; p < 16; ++p) {
        if (p == chunk) continue;
        int pb = base + p;
        while (__hip_atomic_load(&Flag[pb], __ATOMIC_ACQUIRE,
                                 __HIP_MEMORY_SCOPE_AGENT) != SENT)
            __builtin_amdgcn_s_sleep(2);
        const float* pag = Agg + (size_t)pb * 512;
        if (p < chunk)
            carF += __hip_atomic_load(&pag[hh * 64 + cn],
                                      __ATOMIC_RELAXED, __HIP_MEMORY_SCOPE_AGENT);
        else
            carB += __hip_atomic_load(&pag[256 + hh * 64 + cn],
                                      __ATOMIC_RELAXED, __HIP_MEMORY_SCOPE_AGENT);
    }
    sC[0][hh][cn] = carF;
    sC[1][hh][cn] = carB;
    __syncthreads();

    // ---- phase 2: outputs, fragment-packed bf16 stores
    int ksv = lane >> 5, qv = (lane >> 3) & 3, kbv = lane & 7;
    int k0f = ct, k0b = 8 + ct;
    int mtb = b * 32;

    // forward: carry = block carry + lower waves in block
    {
        float em[H_], S[H_];
        #pragma unroll
        for (int h = 0; h < H_; ++h) {
            float s = sC[0][h][lane];
            for (int w = 0; w < wave; ++w) s += sT[0][w][h][lane];
            S[h]  = s;
            ep[h] = expf(fminf(-Lh[h] * (float)t0f, 60.0f));
            em[h] = expf(fmaxf( Lh[h] * (float)t0f, -60.0f));
        }
        #pragma unroll 4
        for (int i = 0; i < 64; ++i) {
            int n  = t0f + i;
            float xv = sxe[i * 64 + lane];
            float y = 0.0f;
            #pragma unroll
            for (int h = 0; h < H_; ++h) {
                S[h]  = fmaf(A[h] * xv, ep[h], S[h]);
                ep[h] = fminf(ep[h] * ri[h], E60P);
                y     = fmaf(ee[h], em[h] * S[h], y);
                em[h] = fmaxf(em[h] * rr[h], E60M);
            }
            int rm = n & 127, mt = mtb + (n >> 7);
            int off = pk_off(mt, rm >> 6, k0f, ksv, (rm >> 4) & 3,
                             qv * 16 + (rm & 15), kbv);
            __hip_bfloat16 yb = __float2bfloat16(y);
            Zp[off] = *(ushort_t*)&yb;
        }
    }

    // backward: carry = block carry + higher waves in block
    {
        float em[H_], S[H_];
        #pragma unroll
        for (int h = 0; h < H_; ++h) {
            float s = sC[1][h][lane];
            for (int w = wave + 1; w < 4; ++w) s += sT[1][w][h][lane];
            S[h]  = s;
            ep[h] = expf(fminf(-Lh[h] * (float)t0b, 60.0f));
            em[h] = expf(fmaxf( Lh[h] * (float)t0b, -60.0f));
        }
        #pragma unroll 4
        for (int j = 0; j < 64; ++j) {
            int n  = t0f + 63 - j;
            float xv = sxe[(63 - j) * 64 + lane];
            float y = 0.0f;
            #pragma unroll
            for (int h = 0; h < H_; ++h) {
                S[h]  = fmaf(A[h] * xv, ep[h], S[h]);
                ep[h] = fminf(ep[h] * ri[h], E60P);
                y     = fmaf(ee[h], em[h] * S[h], y);
                em[h] = fmaxf(em[h] * rr[h], E60M);
            }
            int rm = n & 127, mt = mtb + (n >> 7);
            int off = pk_off(mt, rm >> 6, k0b, ksv, (rm >> 4) & 3,
                             qv * 16 + (rm & 15), kbv);
            __hip_bfloat16 yb = __float2bfloat16(y);
            Zp[off] = *(ushort_t*)&yb;
        }
    }
}

// ---------------------------------------------------------------------------
// cvt + permute proj_w fp32 -> fragment-packed bf16
// ---------------------------------------------------------------------------
__global__ __launch_bounds__(256) void k_cvtw2(const float* __restrict__ w,
                                               ushort_t* __restrict__ Wp)
{
    int i = blockIdx.x * 256 + threadIdx.x;   // 524288 total
    int n = i >> 10, k = i & 1023;
    int nt = n >> 7, rn = n & 127;
    int k0 = k >> 6, kk = k & 63;
    int off = pk_off(nt, rn >> 6, k0, kk >> 5, (rn >> 4) & 3,
                     ((kk >> 3) & 3) * 16 + (rn & 15), kk & 7);
    __hip_bfloat16 vb = __float2bfloat16(w[i]);
    Wp[off] = *(ushort_t*)&vb;
}

// ---------------------------------------------------------------------------
// K4: GEMM out[32768,512] = Z @ W^T + bias, operands fragment-packed,
// barrier-free streaming K-loop. XCD-aware swizzle: xcd = bid&7 = f(mt) so
// the 4 n-tiles of an m-tile run consecutively on ONE XCD (A-tile stays in
// that XCD's 4 MiB L2 -> kills the 4x cross-XCD A refetch).
// ---------------------------------------------------------------------------
__global__ __launch_bounds__(256, 2) void k_gemm2(
    const ushort_t* __restrict__ Zp, const ushort_t* __restrict__ Wp,
    const float* __restrict__ bias, float* __restrict__ out)
{
    __shared__ __align__(16) float stg[32 * 132];   // epilogue staging only

    int tid  = threadIdx.x;
    int lane = tid & 63, wave = tid >> 6;
    int wm   = wave & 1, wn = wave >> 1;
    int fr   = lane & 15, quad = lane >> 4;

    int bid = blockIdx.x;
    int mt  = ((bid >> 5) << 3) | (bid & 7);   // mt & 7 == bid & 7 == XCD
    int nt  = (bid >> 3) & 3;
    int m0  = mt * 128, n0 = nt * 128;

    const ushort_t* Ab = Zp + ((size_t)(mt * 2 + wm) * 16) * 4096 + lane * 8;
    const ushort_t* Bb = Wp + ((size_t)(nt * 2 + wn) * 16) * 4096 + lane * 8;

    floatx4 acc[4][4];
    #pragma unroll
    for (int mf = 0; mf < 4; ++mf)
        #pragma unroll
        for (int nf = 0; nf < 4; ++nf)
            acc[mf][nf] = (floatx4){0.f, 0.f, 0.f, 0.f};

    #pragma unroll
    for (int k0 = 0; k0 < 16; ++k0) {
        short8 af[2][4], bf[2][4];
        #pragma unroll
        for (int ks = 0; ks < 2; ++ks)
            #pragma unroll
            for (int f = 0; f < 4; ++f) {
                af[ks][f] = *(const short8*)(Ab + k0 * 4096 + (ks * 4 + f) * 512);
                bf[ks][f] = *(const short8*)(Bb + k0 * 4096 + (ks * 4 + f) * 512);
            }
        #pragma unroll
        for (int ks = 0; ks < 2; ++ks)
            #pragma unroll
            for (int mf = 0; mf < 4; ++mf)
                #pragma unroll
                for (int nf = 0; nf < 4; ++nf)
                    acc[mf][nf] = __builtin_amdgcn_mfma_f32_16x16x32_bf16(
                        af[ks][mf], bf[ks][nf], acc[mf][nf], 0, 0, 0);
    }

    // ---- LDS-staged epilogue: 4 chunks of 32 rows, coalesced 512 B rows
    int rrow = tid >> 3;                 // 0..31
    int seg  = tid & 7;                  // 0..7
    int gcol = n0 + seg * 16;

    #pragma unroll
    for (int ch = 0; ch < 4; ++ch) {
        if ((wave & 1) == (ch >> 1)) {
            int ml = (ch & 1) * 2;
            #pragma unroll
            for (int mi = 0; mi < 2; ++mi) {
                #pragma unroll
                for (int nf = 0; nf < 4; ++nf) {
                    int col = wn * 64 + nf * 16 + fr;
                    #pragma unroll
                    for (int rg = 0; rg < 4; ++rg) {
                        int row = mi * 16 + quad * 4 + rg;
                        stg[row * 132 + col] = acc[ml + mi][nf][rg];
                    }
                }
            }
        }
        __syncthreads();
        {
            int gm = m0 + ch * 32 + rrow;
            const float* s = &stg[rrow * 132 + seg * 16];
            #pragma unroll
            for (int k = 0; k < 4; ++k) {
                float4 v  = *(const float4*)&s[k * 4];
                float4 bv = *(const float4*)&bias[gcol + k * 4];
                v.x += bv.x; v.y += bv.y; v.z += bv.z; v.w += bv.w;
                *(float4*)&out[(size_t)gm * 512 + gcol + k * 4] = v;
            }
        }
        __syncthreads();
    }
}

// ---------------------------------------------------------------------------
extern "C" void kernel_launch(void* const* d_in, const int* in_sizes, int n_in,
                              void* d_out, int out_size, void* d_ws, size_t ws_size,
                              hipStream_t stream)
{
    const float* x  = (const float*)d_in[0];
    const float* al = (const float*)d_in[1];
    const float* dl = (const float*)d_in[2];
    const float* bl = (const float*)d_in[3];
    const float* et = (const float*)d_in[4];
    const float* pw = (const float*)d_in[5];
    const float* pb = (const float*)d_in[6];
    float* out = (float*)d_out;

    // workspace:
    //   Zp   bf16 packed [32768,1024] : 67,108,864 B
    //   Wp   bf16 packed [512,1024]   :  1,048,576 B
    //   Agg  f32  [1024][2][4][64]    :  2,097,152 B
    //   Flag u32  [1024]              :      4,096 B
    ushort_t*     Zp   = (ushort_t*)d_ws;
    ushort_t*     Wp   = (ushort_t*)((char*)d_ws + 67108864);
    float*        Agg  = (float*)((char*)d_ws + 68157440);
    unsigned int* Flag = (unsigned int*)((char*)d_ws + 70254592);

    hipLaunchKernelGGL(k_cvtw2, dim3(2048), dim3(256), 0, stream, pw, Wp);
    hipLaunchKernelGGL(k_ema,   dim3(1024), dim3(256), 0, stream,
                       x, al, dl, bl, et, Agg, Flag, Zp);
    hipLaunchKernelGGL(k_gemm2, dim3(1024), dim3(256), 0, stream, Zp, Wp, pb, out);
}

// Round 6
// 229.039 us; speedup vs baseline: 3.2202x; 3.2202x over previous
//
#include <hip/hip_runtime.h>
#include <hip/hip_bf16.h>

#define B_ 8
#define N_ 4096
#define C_ 512
#define H_ 4
#define EPS_ 1e-4f
#define E60P 1.14200739e26f   // expf(60)
#define E60M 8.7565108e-27f   // expf(-60)

typedef __attribute__((ext_vector_type(8))) short short8;
typedef __attribute__((ext_vector_type(4))) float floatx4;
typedef __attribute__((ext_vector_type(2))) float floatx2;
typedef unsigned short ushort_t;

__device__ __forceinline__ float sigmoidf_(float v) {
    return 1.0f / (1.0f + expf(-v));
}

// Fragment-packed layout for GEMM operands (Z and W):
//   chunk(tile t, half w, k0, ks, f) = 512 bf16 (1 KiB) in exact MFMA lane
//   order: element lane*8+kb holds Op[t*128+w*64+f*16+(lane&15)]
//                                   [k0*64+ks*32+(lane>>4)*8+kb]
__device__ __forceinline__ int pk_off(int t, int w, int k0, int ks, int f,
                                      int lane8, int kb) {
    return ((((t * 2 + w) * 16 + k0) * 2 + ks) * 4 + f) * 512 + lane8 * 8 + kb;
}

// ---------------------------------------------------------------------------
// K1: fused-direction per-subchunk partial sums, packed-f32 math, 8-deep
// load double-buffer. grid 1024 = chunk(4b)|ct(3b)|b(3b).
// ---------------------------------------------------------------------------
__global__ __launch_bounds__(256) void k_partials3(
    const float* __restrict__ x, const float* __restrict__ al,
    const float* __restrict__ dl, const float* __restrict__ bl,
    float* __restrict__ P)
{
    int bid   = blockIdx.x;
    int chunk = bid & 15;
    int ct    = (bid >> 4) & 7;
    int b     = bid >> 7;
    int lane  = threadIdx.x & 63;
    int wave  = threadIdx.x >> 6;
    int c     = ct * 64 + lane;
    int sub   = chunk * 4 + wave;     // fwd subchunk 0..63
    int t0f   = sub * 64;
    int t0b   = (63 - sub) * 64;      // bwd subchunk start (reversed time)

    float aa[4], dd[4], bb[4];
    { float4 v = ((const float4*)al)[c]; aa[0]=v.x; aa[1]=v.y; aa[2]=v.z; aa[3]=v.w; }
    { float4 v = ((const float4*)dl)[c]; dd[0]=v.x; dd[1]=v.y; dd[2]=v.z; dd[3]=v.w; }
    { float4 v = ((const float4*)bl)[c]; bb[0]=v.x; bb[1]=v.y; bb[2]=v.z; bb[3]=v.w; }

    float A[H_], ri[H_], Lh[H_];
    #pragma unroll
    for (int h = 0; h < H_; ++h) {
        float alpha = sigmoidf_(aa[h]);
        float delta = sigmoidf_(dd[h]);
        float beta  = sigmoidf_(bb[h]);
        A[h] = alpha * beta;
        float r = fminf(fmaxf(1.0f - alpha * delta, EPS_), 1.0f - EPS_);
        Lh[h] = logf(r);
        ri[h] = 1.0f / r;
    }
    const floatx2 E2P = {E60P, E60P};
    floatx2 A2[2]  = {{A[0],  A[1]},  {A[2],  A[3]}};
    floatx2 ri2[2] = {{ri[0], ri[1]}, {ri[2], ri[3]}};

    const float* xp = x + ((size_t)b * N_ + t0f) * C_ + c;

    // ---- forward pass
    floatx2 ep2[2], T2[2];
    #pragma unroll
    for (int p = 0; p < 2; ++p) {
        ep2[p] = (floatx2){expf(fminf(-Lh[2*p]   * (float)t0f, 60.0f)),
                           expf(fminf(-Lh[2*p+1] * (float)t0f, 60.0f))};
        T2[p]  = (floatx2){0.f, 0.f};
    }
    {
        float cur[8];
        #pragma unroll
        for (int j = 0; j < 8; ++j) cur[j] = xp[(size_t)j * C_];
        #pragma unroll 1
        for (int g = 0; g < 8; ++g) {
            float nxt[8];
            if (g < 7) {
                #pragma unroll
                for (int j = 0; j < 8; ++j)
                    nxt[j] = xp[(size_t)(g * 8 + 8 + j) * C_];
            }
            #pragma unroll
            for (int j = 0; j < 8; ++j) {
                floatx2 xv2 = {cur[j], cur[j]};
                #pragma unroll
                for (int p = 0; p < 2; ++p) {
                    T2[p] += (A2[p] * xv2) * ep2[p];
                    ep2[p] = __builtin_elementwise_min(ep2[p] * ri2[p], E2P);
                }
            }
            if (g < 7) {
                #pragma unroll
                for (int j = 0; j < 8; ++j) cur[j] = nxt[j];
            }
        }
        float* pp = P + ((size_t)b * 64 + sub) * (H_ * C_) + c;
        pp[0]      = T2[0].x;  pp[C_]     = T2[0].y;
        pp[2 * C_] = T2[1].x;  pp[3 * C_] = T2[1].y;
    }

    // ---- backward pass: t' = t0b + j, reads row 63-j (cache hit)
    #pragma unroll
    for (int p = 0; p < 2; ++p) {
        ep2[p] = (floatx2){expf(fminf(-Lh[2*p]   * (float)t0b, 60.0f)),
                           expf(fminf(-Lh[2*p+1] * (float)t0b, 60.0f))};
        T2[p]  = (floatx2){0.f, 0.f};
    }
    {
        float cur[8];
        #pragma unroll
        for (int j = 0; j < 8; ++j) cur[j] = xp[(size_t)(63 - j) * C_];
        #pragma unroll 1
        for (int g = 0; g < 8; ++g) {
            float nxt[8];
            if (g < 7) {
                #pragma unroll
                for (int j = 0; j < 8; ++j)
                    nxt[j] = xp[(size_t)(63 - (g * 8 + 8 + j)) * C_];
            }
            #pragma unroll
            for (int j = 0; j < 8; ++j) {
                floatx2 xv2 = {cur[j], cur[j]};
                #pragma unroll
                for (int p = 0; p < 2; ++p) {
                    T2[p] += (A2[p] * xv2) * ep2[p];
                    ep2[p] = __builtin_elementwise_min(ep2[p] * ri2[p], E2P);
                }
            }
            if (g < 7) {
                #pragma unroll
                for (int j = 0; j < 8; ++j) cur[j] = nxt[j];
            }
        }
        float* pp = P + ((size_t)(8 + b) * 64 + (63 - sub)) * (H_ * C_) + c;
        pp[0]      = T2[0].x;  pp[C_]     = T2[0].y;
        pp[2 * C_] = T2[1].x;  pp[3 * C_] = T2[1].y;
    }
}

// ---------------------------------------------------------------------------
// K2: in-place exclusive scan over the 64 subchunks, per (dir,b,c,h)
// ---------------------------------------------------------------------------
__global__ __launch_bounds__(256) void k_scan(float* __restrict__ P)
{
    int bid = blockIdx.x;
    int ct  = bid & 7;
    int b   = (bid >> 3) & 7;
    int dir = bid >> 6;
    int cl  = threadIdx.x & 63;
    int h   = threadIdx.x >> 6;
    int c   = ct * 64 + cl;

    float run = 0.0f;
    float* base = P + ((size_t)(dir * 8 + b) * 64) * (H_ * C_) + h * C_ + c;
    for (int s = 0; s < 64; ++s) {
        float v = base[s * (H_ * C_)];
        base[s * (H_ * C_)] = run;
        run += v;
    }
}

// ---------------------------------------------------------------------------
// K3: fused-direction apply, packed-f32 math, 8-deep load double-buffer;
// writes z directly in fragment-packed bf16 order.
// ---------------------------------------------------------------------------
__global__ __launch_bounds__(256) void k_apply3(
    const float* __restrict__ x, const float* __restrict__ al,
    const float* __restrict__ dl, const float* __restrict__ bl,
    const float* __restrict__ eta, const float* __restrict__ P,
    ushort_t* __restrict__ Zp)
{
    int bid   = blockIdx.x;
    int chunk = bid & 15;
    int ct    = (bid >> 4) & 7;
    int b     = bid >> 7;
    int lane  = threadIdx.x & 63;
    int wave  = threadIdx.x >> 6;
    int c     = ct * 64 + lane;
    int sub   = chunk * 4 + wave;
    int t0f   = sub * 64;
    int t0b   = (63 - sub) * 64;

    int ksv = lane >> 5, qv = (lane >> 3) & 3, kbv = lane & 7;
    int mt  = b * 32 + (t0f >> 7);
    int wq  = (t0f >> 6) & 1;
    // incremental packed offsets: off = offc + (i>>4)*512 + (i&15)*8
    int offcF = pk_off(mt, wq, ct,     ksv, 0, qv * 16, kbv);
    int offcB = pk_off(mt, wq, 8 + ct, ksv, 0, qv * 16, kbv);

    float aa[4], dd[4], bb[4], ee[4];
    { float4 v = ((const float4*)al )[c]; aa[0]=v.x; aa[1]=v.y; aa[2]=v.z; aa[3]=v.w; }
    { float4 v = ((const float4*)dl )[c]; dd[0]=v.x; dd[1]=v.y; dd[2]=v.z; dd[3]=v.w; }
    { float4 v = ((const float4*)bl )[c]; bb[0]=v.x; bb[1]=v.y; bb[2]=v.z; bb[3]=v.w; }
    { float4 v = ((const float4*)eta)[c]; ee[0]=v.x; ee[1]=v.y; ee[2]=v.z; ee[3]=v.w; }

    float A[H_], rr[H_], ri[H_], Lh[H_];
    #pragma unroll
    for (int h = 0; h < H_; ++h) {
        float alpha = sigmoidf_(aa[h]);
        float delta = sigmoidf_(dd[h]);
        float beta  = sigmoidf_(bb[h]);
        A[h] = alpha * beta;
        float r = fminf(fmaxf(1.0f - alpha * delta, EPS_), 1.0f - EPS_);
        Lh[h] = logf(r);
        rr[h] = r;
        ri[h] = 1.0f / r;
    }
    const floatx2 E2P = {E60P, E60P};
    const floatx2 E2M = {E60M, E60M};
    floatx2 A2[2]  = {{A[0],  A[1]},  {A[2],  A[3]}};
    floatx2 ri2[2] = {{ri[0], ri[1]}, {ri[2], ri[3]}};
    floatx2 rr2[2] = {{rr[0], rr[1]}, {rr[2], rr[3]}};
    floatx2 ee2[2] = {{ee[0], ee[1]}, {ee[2], ee[3]}};

    const float* xp = x + ((size_t)b * N_ + t0f) * C_ + c;

    // ---- forward
    {
        const float* cp = P + ((size_t)b * 64 + sub) * (H_ * C_) + c;
        floatx2 ep2[2], em2[2], S2[2];
        #pragma unroll
        for (int p = 0; p < 2; ++p) {
            ep2[p] = (floatx2){expf(fminf(-Lh[2*p]   * (float)t0f, 60.0f)),
                               expf(fminf(-Lh[2*p+1] * (float)t0f, 60.0f))};
            em2[p] = (floatx2){expf(fmaxf( Lh[2*p]   * (float)t0f, -60.0f)),
                               expf(fmaxf( Lh[2*p+1] * (float)t0f, -60.0f))};
            S2[p]  = (floatx2){cp[(2*p) * C_], cp[(2*p+1) * C_]};
        }
        float cur[8];
        #pragma unroll
        for (int j = 0; j < 8; ++j) cur[j] = xp[(size_t)j * C_];
        #pragma unroll 1
        for (int g = 0; g < 8; ++g) {
            float nxt[8];
            if (g < 7) {
                #pragma unroll
                for (int j = 0; j < 8; ++j)
                    nxt[j] = xp[(size_t)(g * 8 + 8 + j) * C_];
            }
            #pragma unroll
            for (int j = 0; j < 8; ++j) {
                int i = g * 8 + j;
                floatx2 xv2 = {cur[j], cur[j]};
                floatx2 acc = {0.f, 0.f};
                #pragma unroll
                for (int p = 0; p < 2; ++p) {
                    S2[p] += (A2[p] * xv2) * ep2[p];
                    ep2[p] = __builtin_elementwise_min(ep2[p] * ri2[p], E2P);
                    acc   += ee2[p] * (em2[p] * S2[p]);
                    em2[p] = __builtin_elementwise_max(em2[p] * rr2[p], E2M);
                }
                float y = acc.x + acc.y;
                __hip_bfloat16 yb = __float2bfloat16(y);
                Zp[offcF + (i >> 4) * 512 + (i & 15) * 8] = *(ushort_t*)&yb;
            }
            if (g < 7) {
                #pragma unroll
                for (int j = 0; j < 8; ++j) cur[j] = nxt[j];
            }
        }
    }

    // ---- backward: t' = t0b + j ascending, output row i = 63 - j
    {
        const float* cp = P + ((size_t)(8 + b) * 64 + (63 - sub)) * (H_ * C_) + c;
        floatx2 ep2[2], em2[2], S2[2];
        #pragma unroll
        for (int p = 0; p < 2; ++p) {
            ep2[p] = (floatx2){expf(fminf(-Lh[2*p]   * (float)t0b, 60.0f)),
                               expf(fminf(-Lh[2*p+1] * (float)t0b, 60.0f))};
            em2[p] = (floatx2){expf(fmaxf( Lh[2*p]   * (float)t0b, -60.0f)),
                               expf(fmaxf( Lh[2*p+1] * (float)t0b, -60.0f))};
            S2[p]  = (floatx2){cp[(2*p) * C_], cp[(2*p+1) * C_]};
        }
        float cur[8];
        #pragma unroll
        for (int j = 0; j < 8; ++j) cur[j] = xp[(size_t)(63 - j) * C_];
        #pragma unroll 1
        for (int g = 0; g < 8; ++g) {
            float nxt[8];
            if (g < 7) {
                #pragma unroll
                for (int j = 0; j < 8; ++j)
                    nxt[j] = xp[(size_t)(63 - (g * 8 + 8 + j)) * C_];
            }
            #pragma unroll
            for (int j = 0; j < 8; ++j) {
                int i = 63 - (g * 8 + j);
                floatx2 xv2 = {cur[j], cur[j]};
                floatx2 acc = {0.f, 0.f};
                #pragma unroll
                for (int p = 0; p < 2; ++p) {
                    S2[p] += (A2[p] * xv2) * ep2[p];
                    ep2[p] = __builtin_elementwise_min(ep2[p] * ri2[p], E2P);
                    acc   += ee2[p] * (em2[p] * S2[p]);
                    em2[p] = __builtin_elementwise_max(em2[p] * rr2[p], E2M);
                }
                float y = acc.x + acc.y;
                __hip_bfloat16 yb = __float2bfloat16(y);
                Zp[offcB + (i >> 4) * 512 + (i & 15) * 8] = *(ushort_t*)&yb;
            }
            if (g < 7) {
                #pragma unroll
                for (int j = 0; j < 8; ++j) cur[j] = nxt[j];
            }
        }
    }
}

// ---------------------------------------------------------------------------
// cvt + permute proj_w fp32 -> fragment-packed bf16
// ---------------------------------------------------------------------------
__global__ __launch_bounds__(256) void k_cvtw2(const float* __restrict__ w,
                                               ushort_t* __restrict__ Wp)
{
    int i = blockIdx.x * 256 + threadIdx.x;   // 524288 total
    int n = i >> 10, k = i & 1023;
    int nt = n >> 7, rn = n & 127;
    int k0 = k >> 6, kk = k & 63;
    int off = pk_off(nt, rn >> 6, k0, kk >> 5, (rn >> 4) & 3,
                     ((kk >> 3) & 3) * 16 + (rn & 15), kk & 7);
    __hip_bfloat16 vb = __float2bfloat16(w[i]);
    Wp[off] = *(ushort_t*)&vb;
}

// ---------------------------------------------------------------------------
// K4: GEMM out[32768,512] = Z @ W^T + bias, operands fragment-packed,
// barrier-free streaming K-loop. XCD swizzle: bid&7 = XCD = mt&7; the 4
// n-tiles of each m-tile run consecutively on ONE XCD (shared L2 -> A-tile
// crosses the fabric once per m-tile).
// ---------------------------------------------------------------------------
__global__ __launch_bounds__(256, 2) void k_gemm2(
    const ushort_t* __restrict__ Zp, const ushort_t* __restrict__ Wp,
    const float* __restrict__ bias, float* __restrict__ out)
{
    __shared__ __align__(16) float stg[32 * 132];   // epilogue staging only

    int tid  = threadIdx.x;
    int lane = tid & 63, wave = tid >> 6;
    int wm   = wave & 1, wn = wave >> 1;
    int fr   = lane & 15, quad = lane >> 4;

    int bid = blockIdx.x;
    int mt  = ((bid >> 5) << 3) | (bid & 7);   // mt & 7 == bid & 7 == XCD
    int nt  = (bid >> 3) & 3;
    int m0  = mt * 128, n0 = nt * 128;

    const ushort_t* Ab = Zp + ((size_t)(mt * 2 + wm) * 16) * 4096 + lane * 8;
    const ushort_t* Bb = Wp + ((size_t)(nt * 2 + wn) * 16) * 4096 + lane * 8;

    floatx4 acc[4][4];
    #pragma unroll
    for (int mf = 0; mf < 4; ++mf)
        #pragma unroll
        for (int nf = 0; nf < 4; ++nf)
            acc[mf][nf] = (floatx4){0.f, 0.f, 0.f, 0.f};

    #pragma unroll
    for (int k0 = 0; k0 < 16; ++k0) {
        short8 af[2][4], bf[2][4];
        #pragma unroll
        for (int ks = 0; ks < 2; ++ks)
            #pragma unroll
            for (int f = 0; f < 4; ++f) {
                af[ks][f] = *(const short8*)(Ab + k0 * 4096 + (ks * 4 + f) * 512);
                bf[ks][f] = *(const short8*)(Bb + k0 * 4096 + (ks * 4 + f) * 512);
            }
        #pragma unroll
        for (int ks = 0; ks < 2; ++ks)
            #pragma unroll
            for (int mf = 0; mf < 4; ++mf)
                #pragma unroll
                for (int nf = 0; nf < 4; ++nf)
                    acc[mf][nf] = __builtin_amdgcn_mfma_f32_16x16x32_bf16(
                        af[ks][mf], bf[ks][nf], acc[mf][nf], 0, 0, 0);
    }

    // ---- LDS-staged epilogue: 4 chunks of 32 rows, coalesced 512 B rows
    int rrow = tid >> 3;                 // 0..31
    int seg  = tid & 7;                  // 0..7
    int gcol = n0 + seg * 16;

    #pragma unroll
    for (int ch = 0; ch < 4; ++ch) {
        if ((wave & 1) == (ch >> 1)) {
            int ml = (ch & 1) * 2;
            #pragma unroll
            for (int mi = 0; mi < 2; ++mi) {
                #pragma unroll
                for (int nf = 0; nf < 4; ++nf) {
                    int col = wn * 64 + nf * 16 + fr;
                    #pragma unroll
                    for (int rg = 0; rg < 4; ++rg) {
                        int row = mi * 16 + quad * 4 + rg;
                        stg[row * 132 + col] = acc[ml + mi][nf][rg];
                    }
                }
            }
        }
        __syncthreads();
        {
            int gm = m0 + ch * 32 + rrow;
            const float* s = &stg[rrow * 132 + seg * 16];
            #pragma unroll
            for (int k = 0; k < 4; ++k) {
                float4 v  = *(const float4*)&s[k * 4];
                float4 bv = *(const float4*)&bias[gcol + k * 4];
                v.x += bv.x; v.y += bv.y; v.z += bv.z; v.w += bv.w;
                *(float4*)&out[(size_t)gm * 512 + gcol + k * 4] = v;
            }
        }
        __syncthreads();
    }
}

// ---------------------------------------------------------------------------
extern "C" void kernel_launch(void* const* d_in, const int* in_sizes, int n_in,
                              void* d_out, int out_size, void* d_ws, size_t ws_size,
                              hipStream_t stream)
{
    const float* x  = (const float*)d_in[0];
    const float* al = (const float*)d_in[1];
    const float* dl = (const float*)d_in[2];
    const float* bl = (const float*)d_in[3];
    const float* et = (const float*)d_in[4];
    const float* pw = (const float*)d_in[5];
    const float* pb = (const float*)d_in[6];
    float* out = (float*)d_out;

    // workspace:
    //   Zp bf16 packed [32768,1024] : 67,108,864 B
    //   P  f32  [2,B,64,H,C]        :  8,388,608 B
    //   Wp bf16 packed [512,1024]   :  1,048,576 B
    ushort_t* Zp = (ushort_t*)d_ws;
    float*    P  = (float*)((char*)d_ws + 67108864);
    ushort_t* Wp = (ushort_t*)((char*)d_ws + 75497472);

    hipLaunchKernelGGL(k_cvtw2,     dim3(2048), dim3(256), 0, stream, pw, Wp);
    hipLaunchKernelGGL(k_partials3, dim3(1024), dim3(256), 0, stream, x, al, dl, bl, P);
    hipLaunchKernelGGL(k_scan,      dim3(128),  dim3(256), 0, stream, P);
    hipLaunchKernelGGL(k_apply3,    dim3(1024), dim3(256), 0, stream, x, al, dl, bl, et, P, Zp);
    hipLaunchKernelGGL(k_gemm2,     dim3(1024), dim3(256), 0, stream, Zp, Wp, pb, out);
}